// Round 14
// baseline (437.282 us; speedup 1.0000x reference)
//
#include <hip/hip_runtime.h>
#include <hip/hip_bf16.h>

#define D_OUT 64
#define K_DIM 512
#define RPB 128            // rows per bucket (pow2)
#define RPB_SHIFT 7
#define EPB 8192           // edges per partition chunk
#define GCAP 3072          // keys capacity per bucket (mean 2046, +22 sigma)
#define RCAP 3072          // LDS record capacity per bucket
#define CPAD 16            // cursor padding: 16 ints = 64 B per counter
#define NBK 1024           // padded bucket-array capacity (782 actual)
#define NGEMM 512          // persistent gemm blocks (2 per CU)

using short8  = __attribute__((ext_vector_type(8))) short;
using floatx4 = __attribute__((ext_vector_type(4))) float;

__device__ inline unsigned short f32_to_bf16(float f) {
    __hip_bfloat16 b = __float2bfloat16(f);          // HW RNE cvt
    return *reinterpret_cast<unsigned short*>(&b);
}

__device__ inline unsigned int pk_bf16(float lo, float hi) {
    __hip_bfloat162 p = __float22bfloat162_rn(make_float2(lo, hi));
    return *reinterpret_cast<unsigned int*>(&p);     // low16 = lo, high16 = hi
}

__device__ inline float bf16lo_f32(unsigned int g) {   // low ushort -> f32
    return __uint_as_float(g << 16);
}
__device__ inline float bf16hi_f32(unsigned int g) {   // high ushort -> f32
    return __uint_as_float(g & 0xFFFF0000u);
}

// ---------------------------------------------------------------------------
// wf = W in MFMA B-FRAGMENT ORDER (64 KB, L2-resident):
//   wf[((nb*16 + sg)*64 + lane)*8 + j] = bf16(W[k][n])
//   k = sg*32 + (lane>>4)*8 + j,  n = nb*16 + (lane&15)
// -> a wave's B load for step sg is wf + nb*8192 + sg*512 + lane*8 (1 KB contig).
// + fused cursor init (bucket segment bases, 64 B-padded)
__global__ void wt_kernel(const float* __restrict__ W, unsigned short* __restrict__ wf,
                          int* __restrict__ cursor, int nbuck) {
    int i = blockIdx.x * blockDim.x + threadIdx.x;
    if (i < D_OUT * K_DIM) {
        int j    = i & 7;
        int lane = (i >> 3) & 63;
        int s    = (i >> 9) & 15;
        int nb   = i >> 13;
        int k  = s * 32 + (lane >> 4) * 8 + j;
        int nn = nb * 16 + (lane & 15);
        wf[i] = f32_to_bf16(W[k * D_OUT + nn]);
    }
    if (i < nbuck) cursor[i * CPAD] = i * GCAP;
}

// ---------------------------------------------------------------------------
// FUSED gemm + part. gemm path v8: PERSISTENT blocks.
// r10-r13: four structural gemm variants (batch, ping-pong, B-coalesce, VGPR
// cap, LDS staging) all 127-135 us with every pipe <5% busy and occupancy
// stuck at 30% despite no limiting resource -> the untested variable is
// block LIFETIME: 782 short blocks each pay full cold-start load latency 8x
// with zero cross-iteration overlap. Fix: 512 persistent gemm blocks (2/CU),
// each looping over row-tiles; body is r12's register version VERBATIM
// (barrier-free -> waves fully decoupled; tile t+1's loads can issue while
// tile t drains).
//   blocks [0, npart)           : part path (r8 proven, FROZEN)
//   blocks [npart, npart+NGEMM) : persistent gemm path
__global__ __launch_bounds__(256, 4) void gemm_part_kernel(
    const float* __restrict__ A, const unsigned short* __restrict__ wf,
    unsigned short* __restrict__ H, int n,
    const int* __restrict__ rows, const int* __restrict__ cols,
    const float* __restrict__ vals, int* __restrict__ cursor,
    int2* __restrict__ keys, int E, int nbuck, int npart, int ngemm) {
    __shared__ int sm[2 * NBK];          // part path: cnt+offs (8 KB); gemm: unused

    const int tid = threadIdx.x;

    if (blockIdx.x < npart) {
        // ------------------------- part path (FROZEN) ----------------------
        int* cnt  = sm;
        int* offs = sm + NBK;
        const int blk = blockIdx.x;

        for (int b = tid; b < nbuck; b += 256) cnt[b] = 0;
        __syncthreads();

        const int base = blk * EPB;
#pragma unroll
        for (int i = 0; i < EPB / 256; i++) {
            int e = base + tid + i * 256;
            if (e < E) atomicAdd(&cnt[rows[e] >> RPB_SHIFT], 1);
        }
        __syncthreads();

        // ONE padded global atomic per non-empty (chunk,bucket)
        for (int b = tid; b < nbuck; b += 256) {
            int c = cnt[b];
            offs[b] = c ? atomicAdd(&cursor[b * CPAD], c) : 0;
        }
        __syncthreads();

        // scatter (bucket-grouped ~84 B contiguous runs)
#pragma unroll
        for (int i = 0; i < EPB / 256; i++) {
            int e = base + tid + i * 256;
            if (e < E) {
                int r = rows[e];
                int c = cols[e];
                float v = vals[e];
                int b = r >> RPB_SHIFT;
                int p = atomicAdd(&offs[b], 1);
                if (p < (b + 1) * GCAP)      // (practically impossible) overflow guard
                    keys[p] = make_int2(c | ((r & (RPB - 1)) << 17), __float_as_int(v));
            }
        }
        return;
    }

    // ------------------- persistent gemm path ------------------------------
    const int gbk  = blockIdx.x - npart;
    const int wv   = tid >> 6;
    const int lane = tid & 63;
    const int ln   = lane & 15;
    const int quad = lane >> 4;
    const int ntile = (n + 127) >> 7;        // 128-row tiles

    const unsigned short* wfl = wf + lane * 8;

    for (int tb = gbk; tb < ntile; tb += ngemm) {
        const int row0 = tb * 128 + wv * 16;     // row set 0
        const int row1 = row0 + 64;              // row set 1

        int a0 = row0 + ln; if (a0 >= n) a0 = n - 1;     // clamp (stores guarded)
        int a1 = row1 + ln; if (a1 >= n) a1 = n - 1;
        const float* Arow0 = A + (size_t)a0 * K_DIM;
        const float* Arow1 = A + (size_t)a1 * K_DIM;

        floatx4 accA0 = {0.f,0.f,0.f,0.f}, accA1 = {0.f,0.f,0.f,0.f};
        floatx4 accA2 = {0.f,0.f,0.f,0.f}, accA3 = {0.f,0.f,0.f,0.f};
        floatx4 accB0 = {0.f,0.f,0.f,0.f}, accB1 = {0.f,0.f,0.f,0.f};
        floatx4 accB2 = {0.f,0.f,0.f,0.f}, accB3 = {0.f,0.f,0.f,0.f};

        for (int h0 = 0; h0 < K_DIM; h0 += 128) {
            // issue all 16 A-loads for this 128-k chunk (both row sets)
            float4 t0[8], t1[8];
#pragma unroll
            for (int s = 0; s < 4; s++) {
                t0[2 * s]     = *reinterpret_cast<const float4*>(Arow0 + h0 + s * 32 + quad * 8);
                t0[2 * s + 1] = *reinterpret_cast<const float4*>(Arow0 + h0 + s * 32 + quad * 8 + 4);
                t1[2 * s]     = *reinterpret_cast<const float4*>(Arow1 + h0 + s * 32 + quad * 8);
                t1[2 * s + 1] = *reinterpret_cast<const float4*>(Arow1 + h0 + s * 32 + quad * 8 + 4);
            }
            // convert to bf16 fragments (packed v_cvt_pk_bf16_f32)
            short8 ab0[4], ab1[4];
#pragma unroll
            for (int s = 0; s < 4; s++) {
                float4 x0 = t0[2 * s], x1 = t0[2 * s + 1];
                int4 pk;
                pk.x = (int)pk_bf16(x0.x, x0.y);
                pk.y = (int)pk_bf16(x0.z, x0.w);
                pk.z = (int)pk_bf16(x1.x, x1.y);
                pk.w = (int)pk_bf16(x1.z, x1.w);
                ab0[s] = *reinterpret_cast<short8*>(&pk);
                float4 y0 = t1[2 * s], y1 = t1[2 * s + 1];
                int4 qk;
                qk.x = (int)pk_bf16(y0.x, y0.y);
                qk.y = (int)pk_bf16(y0.z, y0.w);
                qk.z = (int)pk_bf16(y1.x, y1.y);
                qk.w = (int)pk_bf16(y1.z, y1.w);
                ab1[s] = *reinterpret_cast<short8*>(&qk);
            }
            // MFMA: B fragment loaded once, used by BOTH row sets
#pragma unroll
            for (int s = 0; s < 4; s++) {
                const unsigned short* bb = wfl + h0 * 16 + s * 512;
                short8 b0 = *reinterpret_cast<const short8*>(bb);
                short8 b1 = *reinterpret_cast<const short8*>(bb + 8192);
                short8 b2 = *reinterpret_cast<const short8*>(bb + 16384);
                short8 b3 = *reinterpret_cast<const short8*>(bb + 24576);
                accA0 = __builtin_amdgcn_mfma_f32_16x16x32_bf16(ab0[s], b0, accA0, 0, 0, 0);
                accA1 = __builtin_amdgcn_mfma_f32_16x16x32_bf16(ab0[s], b1, accA1, 0, 0, 0);
                accA2 = __builtin_amdgcn_mfma_f32_16x16x32_bf16(ab0[s], b2, accA2, 0, 0, 0);
                accA3 = __builtin_amdgcn_mfma_f32_16x16x32_bf16(ab0[s], b3, accA3, 0, 0, 0);
                accB0 = __builtin_amdgcn_mfma_f32_16x16x32_bf16(ab1[s], b0, accB0, 0, 0, 0);
                accB1 = __builtin_amdgcn_mfma_f32_16x16x32_bf16(ab1[s], b1, accB1, 0, 0, 0);
                accB2 = __builtin_amdgcn_mfma_f32_16x16x32_bf16(ab1[s], b2, accB2, 0, 0, 0);
                accB3 = __builtin_amdgcn_mfma_f32_16x16x32_bf16(ab1[s], b3, accB3, 0, 0, 0);
            }
        }

        // C/D layout: col = lane&15, row = quad*4 + reg  [m89]
#pragma unroll
        for (int r = 0; r < 4; r++) {
            int gr = row0 + quad * 4 + r;
            if (gr < n) {
                unsigned short* Hr = H + (size_t)gr * D_OUT;
                Hr[ln]      = f32_to_bf16(accA0[r]);
                Hr[16 + ln] = f32_to_bf16(accA1[r]);
                Hr[32 + ln] = f32_to_bf16(accA2[r]);
                Hr[48 + ln] = f32_to_bf16(accA3[r]);
            }
        }
#pragma unroll
        for (int r = 0; r < 4; r++) {
            int gr = row1 + quad * 4 + r;
            if (gr < n) {
                unsigned short* Hr = H + (size_t)gr * D_OUT;
                Hr[ln]      = f32_to_bf16(accB0[r]);
                Hr[16 + ln] = f32_to_bf16(accB1[r]);
                Hr[32 + ln] = f32_to_bf16(accB2[r]);
                Hr[48 + ln] = f32_to_bf16(accB3[r]);
            }
        }
    }
}

// ---------------------------------------------------------------------------
// P4 (r8 proven, FROZEN): one block per bucket. LDS counting sort by
// row-local, then wave-per-row register accumulation, fused ReLU store.
__global__ __launch_bounds__(512) void sort_agg_kernel(
    const unsigned short* __restrict__ h, const int2* __restrict__ keys,
    const int* __restrict__ cursor, float* __restrict__ out, int N) {
    __shared__ int2 rec[RCAP];
    __shared__ int cnt[RPB];
    __shared__ int excl[RPB];
    __shared__ int cur[RPB];
    __shared__ int wtot[2];

    const int tid  = threadIdx.x;
    const int lane = tid & 63;
    const int wv   = tid >> 6;           // 0..7
    const int q    = lane >> 4;          // 0..3  : edge slot within wave
    const int li   = lane & 15;          // 0..15 : 4 cols per lane
    const int b    = blockIdx.x;

    const int start = b * GCAP;
    int m = cursor[b * CPAD] - start;    // final cursor = start + count
    if (m > GCAP) m = GCAP;

    if (tid < RPB) cnt[tid] = 0;
    __syncthreads();

    // count rows
    for (int i = tid; i < m; i += 512) {
        int rl = keys[start + i].x >> 17;
        atomicAdd(&cnt[rl], 1);
    }
    __syncthreads();

    // exclusive scan of 128 counters (2 waves)
    int v = 0, x = 0;
    if (tid < RPB) {
        v = cnt[tid];
        x = v;
#pragma unroll
        for (int d = 1; d < 64; d <<= 1) {
            int y = __shfl_up(x, d, 64);
            if (lane >= d) x += y;
        }
        if (lane == 63) wtot[tid >> 6] = x;
    }
    __syncthreads();
    if (tid < RPB) {
        int base = (tid >= 64) ? wtot[0] : 0;
        int ex = base + x - v;
        excl[tid] = ex;
        cur[tid]  = ex;
    }
    __syncthreads();

    // scatter into row-sorted LDS positions
    for (int i = tid; i < m; i += 512) {
        int2 kv = keys[start + i];
        int rl = kv.x >> 17;
        int p = atomicAdd(&cur[rl], 1);
        if (p < RCAP) rec[p] = kv;
    }
    __syncthreads();

    // aggregate: wave per row; 4 edges per load instruction, 8 in flight.
    const int row0 = b * RPB;
    for (int rl = wv; rl < RPB; rl += 8) {
        int s = excl[rl];
        int e = cur[rl];                 // = excl + count
        float4 acc = {0.f, 0.f, 0.f, 0.f};
        int j = s;
        for (; j + 8 <= e; j += 8) {
            int2 kA = rec[j + q];
            int2 kB = rec[j + 4 + q];
            const uint2 gA = *reinterpret_cast<const uint2*>(
                h + (size_t)(kA.x & 0x1FFFF) * D_OUT + li * 4);
            const uint2 gB = *reinterpret_cast<const uint2*>(
                h + (size_t)(kB.x & 0x1FFFF) * D_OUT + li * 4);
            float vA = __int_as_float(kA.y);
            float vB = __int_as_float(kB.y);
            acc.x += vA * bf16lo_f32(gA.x);
            acc.y += vA * bf16hi_f32(gA.x);
            acc.z += vA * bf16lo_f32(gA.y);
            acc.w += vA * bf16hi_f32(gA.y);
            acc.x += vB * bf16lo_f32(gB.x);
            acc.y += vB * bf16hi_f32(gB.x);
            acc.z += vB * bf16lo_f32(gB.y);
            acc.w += vB * bf16hi_f32(gB.y);
        }
        for (; j < e; j += 4) {
            bool on = (j + q) < e;
            int2 kv = rec[on ? j + q : j];     // j < e, so rec[j] is safe
            const uint2 g = *reinterpret_cast<const uint2*>(
                h + (size_t)(kv.x & 0x1FFFF) * D_OUT + li * 4);
            float vv = on ? __int_as_float(kv.y) : 0.f;
            acc.x += vv * bf16lo_f32(g.x);
            acc.y += vv * bf16hi_f32(g.x);
            acc.z += vv * bf16lo_f32(g.y);
            acc.w += vv * bf16hi_f32(g.y);
        }
        // combine the 4 edge slots (xor 16, then 32)
        acc.x += __shfl_xor(acc.x, 16, 64);
        acc.y += __shfl_xor(acc.y, 16, 64);
        acc.z += __shfl_xor(acc.z, 16, 64);
        acc.w += __shfl_xor(acc.w, 16, 64);
        acc.x += __shfl_xor(acc.x, 32, 64);
        acc.y += __shfl_xor(acc.y, 32, 64);
        acc.z += __shfl_xor(acc.z, 32, 64);
        acc.w += __shfl_xor(acc.w, 32, 64);

        if (q == 0) {
            int gr = row0 + rl;
            if (gr < N) {
                float4 o;
                o.x = fmaxf(acc.x, 0.f);
                o.y = fmaxf(acc.y, 0.f);
                o.z = fmaxf(acc.z, 0.f);
                o.w = fmaxf(acc.w, 0.f);
                *reinterpret_cast<float4*>(out + (size_t)gr * D_OUT + li * 4) = o;
            }
        }
    }
}

// ---------------------------------------------------------------------------
extern "C" void kernel_launch(void* const* d_in, const int* in_sizes, int n_in,
                              void* d_out, int out_size, void* d_ws, size_t ws_size,
                              hipStream_t stream) {
    const float* A    = (const float*)d_in[0];
    const float* W    = (const float*)d_in[1];
    const float* vals = (const float*)d_in[2];
    const int*   rows = (const int*)d_in[3];
    const int*   cols = (const int*)d_in[4];
    float* out = (float*)d_out;

    const int N = out_size / D_OUT;                 // 100000
    const int E = in_sizes[2];                      // 1600000
    const int nbuck = (N + RPB - 1) >> RPB_SHIFT;   // 782
    const int nb = (E + EPB - 1) / EPB;             // 196 (part blocks)

    // workspace layout (keys 8-aligned; h is bf16)
    char* ws = (char*)d_ws;
    unsigned short* h      = (unsigned short*)ws;                          // N*64 bf16
    int2*           keys   = (int2*)(ws + (size_t)N * D_OUT * 2);          // nbuck*GCAP int2
    unsigned short* wf     = (unsigned short*)((char*)keys + (size_t)nbuck * GCAP * 8);
    int*            cursor = (int*)((char*)wf + (size_t)D_OUT * K_DIM * 2); // nbuck*CPAD

    wt_kernel<<<(D_OUT * K_DIM + 255) / 256, 256, 0, stream>>>(W, wf, cursor, nbuck);
    gemm_part_kernel<<<nb + NGEMM, 256, 0, stream>>>(A, wf, h, N,
                                                     rows, cols, vals, cursor, keys,
                                                     E, nbuck, nb, NGEMM);
    sort_agg_kernel<<<nbuck, 512, 0, stream>>>(h, keys, cursor, out, N);
}

// Round 15
// 376.280 us; speedup vs baseline: 1.1621x; 1.1621x over previous
//
#include <hip/hip_runtime.h>
#include <hip/hip_bf16.h>

#define D_OUT 64
#define K_DIM 512
#define RPB 128            // rows per bucket (pow2)
#define RPB_SHIFT 7
#define EPB 8192           // edges per partition chunk
#define GCAP 3072          // keys capacity per bucket (mean 2046, +22 sigma)
#define RCAP 3072          // LDS record capacity per bucket
#define CPAD 16            // cursor padding: 16 ints = 64 B per counter
#define NBK 1024           // padded bucket-array capacity (782 actual)

using short8  = __attribute__((ext_vector_type(8))) short;
using floatx4 = __attribute__((ext_vector_type(4))) float;

__device__ inline unsigned short f32_to_bf16(float f) {
    __hip_bfloat16 b = __float2bfloat16(f);          // HW RNE cvt
    return *reinterpret_cast<unsigned short*>(&b);
}

__device__ inline unsigned int pk_bf16(float lo, float hi) {
    __hip_bfloat162 p = __float22bfloat162_rn(make_float2(lo, hi));
    return *reinterpret_cast<unsigned int*>(&p);     // low16 = lo, high16 = hi
}

__device__ inline float bf16lo_f32(unsigned int g) {   // low ushort -> f32
    return __uint_as_float(g << 16);
}
__device__ inline float bf16hi_f32(unsigned int g) {   // high ushort -> f32
    return __uint_as_float(g & 0xFFFF0000u);
}

// ---------------------------------------------------------------------------
// wf = W in MFMA B-FRAGMENT ORDER (64 KB, L2-resident):
//   wf[((nb*16 + sg)*64 + lane)*8 + j] = bf16(W[k][n])
//   k = sg*32 + (lane>>4)*8 + j,  n = nb*16 + (lane&15)
// -> a wave's B load for step sg is wf + nb*8192 + sg*512 + lane*8 (1 KB contig).
// + fused cursor init (bucket segment bases, 64 B-padded)
__global__ void wt_kernel(const float* __restrict__ W, unsigned short* __restrict__ wf,
                          int* __restrict__ cursor, int nbuck) {
    int i = blockIdx.x * blockDim.x + threadIdx.x;
    if (i < D_OUT * K_DIM) {
        int j    = i & 7;
        int lane = (i >> 3) & 63;
        int s    = (i >> 9) & 15;
        int nb   = i >> 13;
        int k  = s * 32 + (lane >> 4) * 8 + j;
        int nn = nb * 16 + (lane & 15);
        wf[i] = f32_to_bf16(W[k * D_OUT + nn]);
    }
    if (i < nbuck) cursor[i * CPAD] = i * GCAP;
}

// ---------------------------------------------------------------------------
// FUSED gemm + part — REVERT to the r12 best (376.7 us; gemm_part 127 us).
// r14's persistent-block experiment regressed (FETCH 113->199 MB, WRITE
// 52->171 MB): dispatch-ordered short blocks walk A/H sequentially and the
// L3 absorbs ~half of A; persistence destroyed that locality. The 127 us
// gemm_part is a cache-system equilibrium at this decomposition — six
// structural variants (batch, ping-pong, B-coalesce, VGPR cap, LDS staging,
// persistence) all confirmed it as the floor.
//   blocks [0, npart)        : part path (r8 proven, FROZEN)
//   blocks [npart, npart+gb) : gemm path (128 rows/block, double-row waves)
__global__ __launch_bounds__(256, 4) void gemm_part_kernel(
    const float* __restrict__ A, const unsigned short* __restrict__ wf,
    unsigned short* __restrict__ H, int n,
    const int* __restrict__ rows, const int* __restrict__ cols,
    const float* __restrict__ vals, int* __restrict__ cursor,
    int2* __restrict__ keys, int E, int nbuck, int npart) {
    __shared__ int sm[2 * NBK];          // part path: cnt+offs (8 KB); gemm: unused

    const int tid = threadIdx.x;

    if (blockIdx.x < npart) {
        // ------------------------- part path (FROZEN) ----------------------
        int* cnt  = sm;
        int* offs = sm + NBK;
        const int blk = blockIdx.x;

        for (int b = tid; b < nbuck; b += 256) cnt[b] = 0;
        __syncthreads();

        const int base = blk * EPB;
#pragma unroll
        for (int i = 0; i < EPB / 256; i++) {
            int e = base + tid + i * 256;
            if (e < E) atomicAdd(&cnt[rows[e] >> RPB_SHIFT], 1);
        }
        __syncthreads();

        // ONE padded global atomic per non-empty (chunk,bucket)
        for (int b = tid; b < nbuck; b += 256) {
            int c = cnt[b];
            offs[b] = c ? atomicAdd(&cursor[b * CPAD], c) : 0;
        }
        __syncthreads();

        // scatter (bucket-grouped ~84 B contiguous runs)
#pragma unroll
        for (int i = 0; i < EPB / 256; i++) {
            int e = base + tid + i * 256;
            if (e < E) {
                int r = rows[e];
                int c = cols[e];
                float v = vals[e];
                int b = r >> RPB_SHIFT;
                int p = atomicAdd(&offs[b], 1);
                if (p < (b + 1) * GCAP)      // (practically impossible) overflow guard
                    keys[p] = make_int2(c | ((r & (RPB - 1)) << 17), __float_as_int(v));
            }
        }
        return;
    }

    // --------------------------- gemm path ---------------------------------
    const int gbk  = blockIdx.x - npart;
    const int wv   = tid >> 6;
    const int lane = tid & 63;
    const int ln   = lane & 15;
    const int quad = lane >> 4;
    const int row0 = gbk * 128 + wv * 16;    // row set 0
    const int row1 = row0 + 64;              // row set 1

    int a0 = row0 + ln; if (a0 >= n) a0 = n - 1;     // clamp (stores guarded)
    int a1 = row1 + ln; if (a1 >= n) a1 = n - 1;
    const float* Arow0 = A + (size_t)a0 * K_DIM;
    const float* Arow1 = A + (size_t)a1 * K_DIM;
    const unsigned short* wfl = wf + lane * 8;       // + sg*512 per k-step

    floatx4 accA0 = {0.f,0.f,0.f,0.f}, accA1 = {0.f,0.f,0.f,0.f};
    floatx4 accA2 = {0.f,0.f,0.f,0.f}, accA3 = {0.f,0.f,0.f,0.f};
    floatx4 accB0 = {0.f,0.f,0.f,0.f}, accB1 = {0.f,0.f,0.f,0.f};
    floatx4 accB2 = {0.f,0.f,0.f,0.f}, accB3 = {0.f,0.f,0.f,0.f};

    for (int h0 = 0; h0 < K_DIM; h0 += 128) {
        // issue all 16 A-loads for this 128-k chunk (both row sets, batched)
        float4 t0[8], t1[8];
#pragma unroll
        for (int s = 0; s < 4; s++) {
            t0[2 * s]     = *reinterpret_cast<const float4*>(Arow0 + h0 + s * 32 + quad * 8);
            t0[2 * s + 1] = *reinterpret_cast<const float4*>(Arow0 + h0 + s * 32 + quad * 8 + 4);
            t1[2 * s]     = *reinterpret_cast<const float4*>(Arow1 + h0 + s * 32 + quad * 8);
            t1[2 * s + 1] = *reinterpret_cast<const float4*>(Arow1 + h0 + s * 32 + quad * 8 + 4);
        }
        // convert to bf16 fragments (packed v_cvt_pk_bf16_f32)
        short8 ab0[4], ab1[4];
#pragma unroll
        for (int s = 0; s < 4; s++) {
            float4 x0 = t0[2 * s], x1 = t0[2 * s + 1];
            int4 pk;
            pk.x = (int)pk_bf16(x0.x, x0.y);
            pk.y = (int)pk_bf16(x0.z, x0.w);
            pk.z = (int)pk_bf16(x1.x, x1.y);
            pk.w = (int)pk_bf16(x1.z, x1.w);
            ab0[s] = *reinterpret_cast<short8*>(&pk);
            float4 y0 = t1[2 * s], y1 = t1[2 * s + 1];
            int4 qk;
            qk.x = (int)pk_bf16(y0.x, y0.y);
            qk.y = (int)pk_bf16(y0.z, y0.w);
            qk.z = (int)pk_bf16(y1.x, y1.y);
            qk.w = (int)pk_bf16(y1.z, y1.w);
            ab1[s] = *reinterpret_cast<short8*>(&qk);
        }
        // MFMA: B fragment loaded once, used by BOTH row sets
#pragma unroll
        for (int s = 0; s < 4; s++) {
            const unsigned short* bb = wfl + h0 * 16 + s * 512;  // sg=(h0/32+s)
            short8 b0 = *reinterpret_cast<const short8*>(bb);
            short8 b1 = *reinterpret_cast<const short8*>(bb + 8192);
            short8 b2 = *reinterpret_cast<const short8*>(bb + 16384);
            short8 b3 = *reinterpret_cast<const short8*>(bb + 24576);
            accA0 = __builtin_amdgcn_mfma_f32_16x16x32_bf16(ab0[s], b0, accA0, 0, 0, 0);
            accA1 = __builtin_amdgcn_mfma_f32_16x16x32_bf16(ab0[s], b1, accA1, 0, 0, 0);
            accA2 = __builtin_amdgcn_mfma_f32_16x16x32_bf16(ab0[s], b2, accA2, 0, 0, 0);
            accA3 = __builtin_amdgcn_mfma_f32_16x16x32_bf16(ab0[s], b3, accA3, 0, 0, 0);
            accB0 = __builtin_amdgcn_mfma_f32_16x16x32_bf16(ab1[s], b0, accB0, 0, 0, 0);
            accB1 = __builtin_amdgcn_mfma_f32_16x16x32_bf16(ab1[s], b1, accB1, 0, 0, 0);
            accB2 = __builtin_amdgcn_mfma_f32_16x16x32_bf16(ab1[s], b2, accB2, 0, 0, 0);
            accB3 = __builtin_amdgcn_mfma_f32_16x16x32_bf16(ab1[s], b3, accB3, 0, 0, 0);
        }
    }

    // C/D layout: col = lane&15, row = quad*4 + reg  [m89]
#pragma unroll
    for (int r = 0; r < 4; r++) {
        int gr = row0 + quad * 4 + r;
        if (gr < n) {
            unsigned short* Hr = H + (size_t)gr * D_OUT;
            Hr[ln]      = f32_to_bf16(accA0[r]);
            Hr[16 + ln] = f32_to_bf16(accA1[r]);
            Hr[32 + ln] = f32_to_bf16(accA2[r]);
            Hr[48 + ln] = f32_to_bf16(accA3[r]);
        }
    }
#pragma unroll
    for (int r = 0; r < 4; r++) {
        int gr = row1 + quad * 4 + r;
        if (gr < n) {
            unsigned short* Hr = H + (size_t)gr * D_OUT;
            Hr[ln]      = f32_to_bf16(accB0[r]);
            Hr[16 + ln] = f32_to_bf16(accB1[r]);
            Hr[32 + ln] = f32_to_bf16(accB2[r]);
            Hr[48 + ln] = f32_to_bf16(accB3[r]);
        }
    }
}

// ---------------------------------------------------------------------------
// P4 (r8 proven, FROZEN): one block per bucket. LDS counting sort by
// row-local, then wave-per-row register accumulation, fused ReLU store.
__global__ __launch_bounds__(512) void sort_agg_kernel(
    const unsigned short* __restrict__ h, const int2* __restrict__ keys,
    const int* __restrict__ cursor, float* __restrict__ out, int N) {
    __shared__ int2 rec[RCAP];
    __shared__ int cnt[RPB];
    __shared__ int excl[RPB];
    __shared__ int cur[RPB];
    __shared__ int wtot[2];

    const int tid  = threadIdx.x;
    const int lane = tid & 63;
    const int wv   = tid >> 6;           // 0..7
    const int q    = lane >> 4;          // 0..3  : edge slot within wave
    const int li   = lane & 15;          // 0..15 : 4 cols per lane
    const int b    = blockIdx.x;

    const int start = b * GCAP;
    int m = cursor[b * CPAD] - start;    // final cursor = start + count
    if (m > GCAP) m = GCAP;

    if (tid < RPB) cnt[tid] = 0;
    __syncthreads();

    // count rows
    for (int i = tid; i < m; i += 512) {
        int rl = keys[start + i].x >> 17;
        atomicAdd(&cnt[rl], 1);
    }
    __syncthreads();

    // exclusive scan of 128 counters (2 waves)
    int v = 0, x = 0;
    if (tid < RPB) {
        v = cnt[tid];
        x = v;
#pragma unroll
        for (int d = 1; d < 64; d <<= 1) {
            int y = __shfl_up(x, d, 64);
            if (lane >= d) x += y;
        }
        if (lane == 63) wtot[tid >> 6] = x;
    }
    __syncthreads();
    if (tid < RPB) {
        int base = (tid >= 64) ? wtot[0] : 0;
        int ex = base + x - v;
        excl[tid] = ex;
        cur[tid]  = ex;
    }
    __syncthreads();

    // scatter into row-sorted LDS positions
    for (int i = tid; i < m; i += 512) {
        int2 kv = keys[start + i];
        int rl = kv.x >> 17;
        int p = atomicAdd(&cur[rl], 1);
        if (p < RCAP) rec[p] = kv;
    }
    __syncthreads();

    // aggregate: wave per row; 4 edges per load instruction, 8 in flight.
    const int row0 = b * RPB;
    for (int rl = wv; rl < RPB; rl += 8) {
        int s = excl[rl];
        int e = cur[rl];                 // = excl + count
        float4 acc = {0.f, 0.f, 0.f, 0.f};
        int j = s;
        for (; j + 8 <= e; j += 8) {
            int2 kA = rec[j + q];
            int2 kB = rec[j + 4 + q];
            const uint2 gA = *reinterpret_cast<const uint2*>(
                h + (size_t)(kA.x & 0x1FFFF) * D_OUT + li * 4);
            const uint2 gB = *reinterpret_cast<const uint2*>(
                h + (size_t)(kB.x & 0x1FFFF) * D_OUT + li * 4);
            float vA = __int_as_float(kA.y);
            float vB = __int_as_float(kB.y);
            acc.x += vA * bf16lo_f32(gA.x);
            acc.y += vA * bf16hi_f32(gA.x);
            acc.z += vA * bf16lo_f32(gA.y);
            acc.w += vA * bf16hi_f32(gA.y);
            acc.x += vB * bf16lo_f32(gB.x);
            acc.y += vB * bf16hi_f32(gB.x);
            acc.z += vB * bf16lo_f32(gB.y);
            acc.w += vB * bf16hi_f32(gB.y);
        }
        for (; j < e; j += 4) {
            bool on = (j + q) < e;
            int2 kv = rec[on ? j + q : j];     // j < e, so rec[j] is safe
            const uint2 g = *reinterpret_cast<const uint2*>(
                h + (size_t)(kv.x & 0x1FFFF) * D_OUT + li * 4);
            float vv = on ? __int_as_float(kv.y) : 0.f;
            acc.x += vv * bf16lo_f32(g.x);
            acc.y += vv * bf16hi_f32(g.x);
            acc.z += vv * bf16lo_f32(g.y);
            acc.w += vv * bf16hi_f32(g.y);
        }
        // combine the 4 edge slots (xor 16, then 32)
        acc.x += __shfl_xor(acc.x, 16, 64);
        acc.y += __shfl_xor(acc.y, 16, 64);
        acc.z += __shfl_xor(acc.z, 16, 64);
        acc.w += __shfl_xor(acc.w, 16, 64);
        acc.x += __shfl_xor(acc.x, 32, 64);
        acc.y += __shfl_xor(acc.y, 32, 64);
        acc.z += __shfl_xor(acc.z, 32, 64);
        acc.w += __shfl_xor(acc.w, 32, 64);

        if (q == 0) {
            int gr = row0 + rl;
            if (gr < N) {
                float4 o;
                o.x = fmaxf(acc.x, 0.f);
                o.y = fmaxf(acc.y, 0.f);
                o.z = fmaxf(acc.z, 0.f);
                o.w = fmaxf(acc.w, 0.f);
                *reinterpret_cast<float4*>(out + (size_t)gr * D_OUT + li * 4) = o;
            }
        }
    }
}

// ---------------------------------------------------------------------------
extern "C" void kernel_launch(void* const* d_in, const int* in_sizes, int n_in,
                              void* d_out, int out_size, void* d_ws, size_t ws_size,
                              hipStream_t stream) {
    const float* A    = (const float*)d_in[0];
    const float* W    = (const float*)d_in[1];
    const float* vals = (const float*)d_in[2];
    const int*   rows = (const int*)d_in[3];
    const int*   cols = (const int*)d_in[4];
    float* out = (float*)d_out;

    const int N = out_size / D_OUT;                 // 100000
    const int E = in_sizes[2];                      // 1600000
    const int nbuck = (N + RPB - 1) >> RPB_SHIFT;   // 782
    const int nb = (E + EPB - 1) / EPB;             // 196 (part blocks)
    const int gb = (N + 127) / 128;                 // 782 (gemm blocks, 128 rows each)

    // workspace layout (keys 8-aligned; h is bf16)
    char* ws = (char*)d_ws;
    unsigned short* h      = (unsigned short*)ws;                          // N*64 bf16
    int2*           keys   = (int2*)(ws + (size_t)N * D_OUT * 2);          // nbuck*GCAP int2
    unsigned short* wf     = (unsigned short*)((char*)keys + (size_t)nbuck * GCAP * 8);
    int*            cursor = (int*)((char*)wf + (size_t)D_OUT * K_DIM * 2); // nbuck*CPAD

    wt_kernel<<<(D_OUT * K_DIM + 255) / 256, 256, 0, stream>>>(W, wf, cursor, nbuck);
    gemm_part_kernel<<<nb + gb, 256, 0, stream>>>(A, wf, h, N,
                                                  rows, cols, vals, cursor, keys,
                                                  E, nbuck, nb);
    sort_agg_kernel<<<nbuck, 512, 0, stream>>>(h, keys, cursor, out, N);
}